// Round 7
// baseline (18195.972 us; speedup 1.0000x reference)
//
#include <hip/hip_runtime.h>
#include <stdint.h>

#define N_NEUR  1024
#define N_INP   256
#define N_OUTC  32
#define T_STEPS 500
#define BATCH   64
#define N_DEL   8
#define NB      (N_NEUR*BATCH)     // 65536, layout [n][b], b fastest
#define HSLOTS  132                // ring: live window is 131 steps -> no aliasing
#define CAP     256                // per-(o,d) record capacity (mean 128, 12 sigma)
#define H1RING  64                 // h1 ring depth (steps), power of 2
#define TROWS   128                // staged e-rows per tile (8 tiles per slot)

// ---------------------------------------------------------------------------
// inpT[t][c][b] = inputs[b][t][c]
__global__ __launch_bounds__(256) void transpose_inp(const float* __restrict__ inp,
                                                     float* __restrict__ inpT) {
    __shared__ float L[N_INP * 64];
    int t = blockIdx.x;
    int tid = threadIdx.x;                   // = c
    for (int b = 0; b < 64; ++b) {
        float v = inp[((size_t)b * T_STEPS + t) * N_INP + tid];
        L[tid * 64 + (b ^ (tid & 63))] = v;
    }
    __syncthreads();
    int lane = tid & 63;
    int wv   = tid >> 6;
    for (int cc = 0; cc < 64; ++cc) {
        int c = cc * 4 + wv;
        inpT[((size_t)t * N_INP + c) * 64 + lane] = L[c * 64 + (lane ^ (c & 63))];
    }
}

// w_inT[n][c] = w_in[c][n]
__global__ __launch_bounds__(256) void transpose_win(const float* __restrict__ w_in,
                                                     float* __restrict__ w_inT) {
    int i = blockIdx.x * 256 + threadIdx.x;  // 262144
    int n = i >> 8, c = i & 255;
    w_inT[i] = w_in[(size_t)c * N_NEUR + n];
}

// ---------------------------------------------------------------------------
// CSR build. Records e-ASCENDING per (o,d) (load-bearing for bit-exact order).
// Round-7 changes: (a) pad records use e=1023 (y=1023*64) so e stays
// non-decreasing incl. pads (G=0 -> inert, address valid); (b) emit off2:
// per (o,d), 9 tile boundaries (first position with e >= j*128).
__global__ __launch_bounds__(64) void build_csr(const float* __restrict__ w,
                                                const float* __restrict__ signs,
                                                const float* __restrict__ dmap,
                                                uint2* __restrict__ recs,
                                                int* __restrict__ cnt,
                                                int* __restrict__ off2) {
    int o = blockIdx.x * 64 + threadIdx.x;   // 16 blocks x 64 lanes
    int d = blockIdx.y;                      // 8
    int c = 0;
    uint2* seg = recs + ((size_t)o * N_DEL + d) * CAP;
    for (int e = 0; e < N_NEUR; ++e) {
        float m = dmap[((size_t)d * N_NEUR + e) * N_NEUR + o];  // coalesced over o
        if (m != 0.f) {
            float G = signs[e] * fabsf(w[(size_t)e * N_NEUR + o]);
            if (c < CAP) seg[c] = make_uint2(__float_as_uint(G), (unsigned)(e * 64));
            ++c;
        }
    }
    if (c > CAP) c = CAP;
    int c4 = (c + 3) & ~3;                // pad to multiple of 4
    for (; c < c4; ++c) seg[c] = make_uint2(0u, (unsigned)((N_NEUR - 1) * 64));
    cnt[o * N_DEL + d] = c4;
    // tile boundaries (e non-decreasing incl. pads)
    int b2 = 0;
    for (int j = 0; j <= 8; ++j) {
        while (b2 < c4 && (int)(seg[b2].y >> 6) < j * TROWS) ++b2;
        off2[((size_t)o * N_DEL + d) * 9 + j] = b2;
    }
}

// ---------------------------------------------------------------------------
// h1 ring precompute (bit-exact, unchanged).
__global__ __launch_bounds__(256) void h1_chunk(int t0,
        const float* __restrict__ inpT, const float* __restrict__ w_inT,
        float* __restrict__ h1r) {
    __shared__ float Li[N_INP * 64];   // 64 KB
    __shared__ float Lp[4 * 64];
    int s     = t0 + blockIdx.x;
    int ntile = blockIdx.y;            // 16 tiles x 64 n
    int tid   = threadIdx.x;
    int lane  = tid & 63;
    int wv    = tid >> 6;
    const float4* src = (const float4*)(inpT + (size_t)s * (N_INP * 64));
    float4* dst = (float4*)Li;
    for (int k = tid; k < (N_INP * 64) / 4; k += 256) dst[k] = src[k];
    __syncthreads();
    for (int nn = 0; nn < 64; ++nn) {
        int n = ntile * 64 + nn;
        float hp = 0.f;
        const float* wr = w_inT + n * N_INP + wv * 64;   // uniform -> s_load
#pragma unroll 8
        for (int c2 = 0; c2 < 64; ++c2)
            hp = fmaf(Li[(wv * 64 + c2) * 64 + lane], wr[c2], hp);
        Lp[wv * 64 + lane] = hp;
        __syncthreads();
        if (wv == 0)
            h1r[(size_t)(s & (H1RING - 1)) * NB + n * 64 + lane] =
                Lp[lane] + Lp[64 + lane] + Lp[128 + lane] + Lp[192 + lane];
        __syncthreads();
    }
}

// ---------------------------------------------------------------------------
// Round-7: delay-major LDS-staged gather. Block = (ot, dp, sidx):
// 64 o-tiles x 4 d-pairs x 2 steps = 512 blocks x 512 threads (2 blocks/CU,
// 16 waves/CU; LDS 2x32KB dbuf + tables = ~67KB). Per segment d: sweep the
// tau-slot in 8 tiles of 128 e-rows, double-buffered (reg-staged); each wave
// owns 2 o's and walks their CSR records tile-by-tile from global (sequential,
// L1-friendly), serving row data from LDS.
// Bit-exact vs round-6: per (o,d) chain q processes positions == q (mod 4)
// ascending (tiles ascending = positions ascending; boundary quads predicated
// with g=0 -> fmaf(0,x,acc)==acc; address clamped into staged range so reads
// are valid staged floats); acc carries across tiles and segments; same
// shfl_xor 16/32 tree; partials P summed dp0..3 by step_point (round-5 order).
__global__ __launch_bounds__(512, 4) void step_dmaj(int t0,
        const uint2* __restrict__ recs, const int* __restrict__ off2,
        const int* __restrict__ delays, const float* __restrict__ histc,
        float* __restrict__ P) {
    __shared__ float buf[2][TROWS * 64];   // 2 x 32 KB
    __shared__ int   Soff2[16 * 2 * 9];    // per (o_local, seg): 9 boundaries
    int bid  = blockIdx.x;                 // 512
    int sidx = bid & 1;
    int dp   = (bid >> 1) & 3;
    int ot   = bid >> 3;                   // 0..63
    int tid  = threadIdx.x;
    int lane = tid & 63;
    int wv   = __builtin_amdgcn_readfirstlane(tid >> 6);   // 0..7
    int q    = lane >> 4;                  // record-in-quad
    int bq   = lane & 15;                  // b-quad

    // stage tile-boundary table for this block's 16 o's x 2 segs
    for (int i = tid; i < 16 * 2 * 9; i += 512) {
        int ol = i / 18, rem = i % 18, sg = rem / 9, j = rem % 9;
        Soff2[i] = off2[(((size_t)(ot * 16 + ol)) * N_DEL + (2 * dp + sg)) * 9 + j];
    }
    __syncthreads();

    float4 acc[2];
    acc[0] = make_float4(0.f, 0.f, 0.f, 0.f);
    acc[1] = make_float4(0.f, 0.f, 0.f, 0.f);

#pragma unroll
    for (int sg = 0; sg < 2; ++sg) {
        int d  = 2 * dp + sg;
        int dl = __builtin_amdgcn_readfirstlane(delays[d]);
        int tau = t0 + sidx - 1 - dl;
        if (tau < 0) continue;             // seg contributes nothing (acc kept)
        const float* slot = histc + (size_t)(tau % HSLOTS) * NB;
        // prologue: load tile 0 into regs (64B/thread)
        float4 r0, r1, r2, r3;
        {
            const float4* src = (const float4*)slot;
            int base = tid * 4;
            r0 = src[base]; r1 = src[base + 1]; r2 = src[base + 2]; r3 = src[base + 3];
        }
        for (int j = 0; j < 8; ++j) {
            // write staged regs -> buf[j&1]
            {
                float4* B = (float4*)buf[j & 1];
                int base = tid * 4;
                B[base] = r0; B[base + 1] = r1; B[base + 2] = r2; B[base + 3] = r3;
            }
            __syncthreads();
            // issue next tile's loads (consumed at next write; compiler waits)
            if (j < 7) {
                const float4* src = (const float4*)(slot + (size_t)(j + 1) * TROWS * 64);
                int base = tid * 4;
                r0 = src[base]; r1 = src[base + 1]; r2 = src[base + 2]; r3 = src[base + 3];
            }
            // compute tile j: rows [j*128, (j+1)*128) served from LDS
            const float* LB = buf[j & 1];
#pragma unroll
            for (int oi = 0; oi < 2; ++oi) {
                int ol = wv * 2 + oi;
                int o  = ot * 16 + ol;
                int pb = Soff2[(ol * 2 + sg) * 9 + j];
                int pe = Soff2[(ol * 2 + sg) * 9 + j + 1];
                const uint2* R = recs + ((size_t)o * N_DEL + d) * CAP;
#pragma unroll 4
                for (int k = (pb & ~3); k < pe; k += 4) {
                    int pos = k + q;
                    bool v = (pos >= pb) && (pos < pe);
                    uint2 r = R[v ? pos : pb];           // clamped: valid record
                    float g = v ? __uint_as_float(r.x) : 0.f;
                    int ro  = v ? (int)(r.y - (unsigned)(j * TROWS * 64)) : 0;
                    float4 a = *((const float4*)(LB + ro) + bq);
                    acc[oi].x = fmaf(g, a.x, acc[oi].x);
                    acc[oi].y = fmaf(g, a.y, acc[oi].y);
                    acc[oi].z = fmaf(g, a.z, acc[oi].z);
                    acc[oi].w = fmaf(g, a.w, acc[oi].w);
                }
            }
            __syncthreads();
        }
    }
    // q-reduce (same tree as always) and write partials
#pragma unroll
    for (int oi = 0; oi < 2; ++oi) {
        float4 a = acc[oi];
        a.x += __shfl_xor(a.x, 16); a.x += __shfl_xor(a.x, 32);
        a.y += __shfl_xor(a.y, 16); a.y += __shfl_xor(a.y, 32);
        a.z += __shfl_xor(a.z, 16); a.z += __shfl_xor(a.z, 32);
        a.w += __shfl_xor(a.w, 16); a.w += __shfl_xor(a.w, 32);
        if (lane < 16) {
            int o = ot * 16 + wv * 2 + oi;
            *((float4*)(P + (((size_t)sidx * N_NEUR + o) * 4 + dp) * 64 + lane * 4)) = a;
        }
    }
}

// ---------------------------------------------------------------------------
// POINTWISE kernel (round-5, bench-proven). Sums the 4 d-pair partials in
// dp0+dp1+dp2+dp3 order, then the two serial pointwise steps.
__global__ __launch_bounds__(256) void step_point(int t0,
        const float* __restrict__ P, const float* __restrict__ h1r,
        const float* __restrict__ p,
        float* __restrict__ histc, float* __restrict__ mem,
        float* __restrict__ wp_arr, unsigned long long* __restrict__ spk) {
    int i    = blockIdx.x * 256 + threadIdx.x;   // 65536 = 1024 o * 64 b
    int o    = i >> 6;
    int lane = i & 63;
    float pn = p[o];
    float pd = (pn < 0.f) ? 1.f : 0.f;
    float m = mem[i];
    float w = wp_arr[i];
#pragma unroll
    for (int sidx = 0; sidx < 2; ++sidx) {
        int s = t0 + sidx;
        const float* Pp = P + ((size_t)sidx * N_NEUR + o) * 4 * 64 + lane;
        float syn = Pp[0] + Pp[64] + Pp[128] + Pp[192];
        float h1 = h1r[(size_t)(s & (H1RING - 1)) * NB + i];
        float out = (m - 1.f > 0.f) ? 1.f : 0.f;
        w = w * 0.95f + out * pn * (1.f + pd * w);
        histc[(size_t)(s % HSLOTS) * NB + i] = out * (1.f + w);
        m = 0.9f * m + h1 + syn - out;
        unsigned long long mask = __ballot(out > 0.f);
        if (lane == 0) spk[(size_t)s * N_NEUR + o] = mask;
    }
    mem[i] = m;
    wp_arr[i] = w;
}

// ---------------------------------------------------------------------------
// h2[t][b][o] = sum_n spk_bit(t,n,b) * w_out[n][o]
__global__ __launch_bounds__(256) void h2_gemm(const unsigned long long* __restrict__ spk,
                                               const float* __restrict__ w_out,
                                               float* __restrict__ h2) {
    int t = blockIdx.x;
    int lane = threadIdx.x & 63;     // = b
    int wv   = threadIdx.x >> 6;
    int o0 = wv * 8;
    float acc[8];
#pragma unroll
    for (int j = 0; j < 8; ++j) acc[j] = 0.f;
    for (int n = 0; n < N_NEUR; ++n) {
        unsigned long long mask = spk[(size_t)t * N_NEUR + n];   // uniform
        float s = (float)((mask >> lane) & 1ULL);
        const float* wr = w_out + n * N_OUTC + o0;               // uniform
#pragma unroll
        for (int j = 0; j < 8; ++j) acc[j] = fmaf(s, wr[j], acc[j]);
    }
#pragma unroll
    for (int j = 0; j < 8; ++j)
        h2[((size_t)t * BATCH + lane) * N_OUTC + o0 + j] = acc[j];
}

// out[b][t][o] : leaky-integrator scan over h2
__global__ __launch_bounds__(256) void out_scan(const float* __restrict__ h2,
                                                float* __restrict__ out) {
    int tid = blockIdx.x * 256 + threadIdx.x;   // 2048 = 64b * 32o
    int o = tid & 31;
    int b = tid >> 5;
    float acc = 0.f;
    for (int t = 0; t < T_STEPS; ++t) {
        acc = 0.9f * acc + h2[((size_t)t * BATCH + b) * N_OUTC + o];
        out[((size_t)b * T_STEPS + t) * N_OUTC + o] = acc;
    }
}

// ---------------------------------------------------------------------------
extern "C" void kernel_launch(void* const* d_in, const int* in_sizes, int n_in,
                              void* d_out, int out_size, void* d_ws, size_t ws_size,
                              hipStream_t stream) {
    (void)in_sizes; (void)n_in; (void)out_size; (void)ws_size;
    const float* inputs = (const float*)d_in[0];
    const float* w      = (const float*)d_in[1];
    const float* w_in   = (const float*)d_in[2];
    const float* w_out  = (const float*)d_in[3];
    const float* signs  = (const float*)d_in[4];
    const float* p      = (const float*)d_in[5];
    const float* dmap   = (const float*)d_in[6];
    const int*   delays = (const int*)d_in[7];
    float* out = (float*)d_out;

    // workspace layout (~109 MiB total, under proven 120.6 MiB)
    float* ws    = (float*)d_ws;
    float* inpT  = ws;                                    //  8,192,000 f
    float* w_inT = inpT + (size_t)T_STEPS * N_INP * 64;   //    262,144 f
    float* histc = w_inT + (size_t)N_NEUR * N_INP;        //  8,650,752 f
    float* h1r   = histc + (size_t)HSLOTS * NB;           //  4,194,304 f
    float* mem   = h1r + (size_t)H1RING * NB;             //     65,536 f
    float* wp    = mem + NB;                              //     65,536 f
    float* h2    = wp + NB;                               //  1,024,000 f
    int*   cnt   = (int*)(h2 + (size_t)T_STEPS * BATCH * N_OUTC);  // 8192 i
    uint2* recs  = (uint2*)(cnt + N_NEUR * N_DEL);        //  2,097,152 uint2
    unsigned long long* spk =
        (unsigned long long*)(recs + (size_t)N_NEUR * N_DEL * CAP); // 512,000 ull
    int*   off2  = (int*)(spk + (size_t)T_STEPS * N_NEUR);          // 73,728 i
    float* P     = (float*)(off2 + (size_t)N_NEUR * N_DEL * 9);     // 524,288 f

    hipMemsetAsync(histc, 0, sizeof(float) * (size_t)HSLOTS * NB, stream);
    hipMemsetAsync(mem, 0, sizeof(float) * (size_t)2 * NB, stream);  // mem+wp adjacent

    transpose_inp<<<T_STEPS, 256, 0, stream>>>(inputs, inpT);
    transpose_win<<<(N_NEUR * N_INP) / 256, 256, 0, stream>>>(w_in, w_inT);
    build_csr<<<dim3(16, 8), 64, 0, stream>>>(w, signs, dmap, recs, cnt, off2);

    for (int t0 = 0; t0 < T_STEPS; t0 += 2) {
        if ((t0 & (H1RING - 1)) == 0) {
            int ns = T_STEPS - t0; if (ns > H1RING) ns = H1RING;
            h1_chunk<<<dim3(ns, 16), 256, 0, stream>>>(t0, inpT, w_inT, h1r);
        }
        step_dmaj<<<512, 512, 0, stream>>>(t0, recs, off2, delays, histc, P);
        step_point<<<NB / 256, 256, 0, stream>>>(t0, P, h1r, p, histc, mem, wp, spk);
    }

    h2_gemm<<<T_STEPS, 256, 0, stream>>>(spk, w_out, h2);
    out_scan<<<8, 256, 0, stream>>>(h2, out);
}

// Round 8
// 8136.862 us; speedup vs baseline: 2.2362x; 2.2362x over previous
//
#include <hip/hip_runtime.h>
#include <stdint.h>

#define N_NEUR  1024
#define N_INP   256
#define N_OUTC  32
#define T_STEPS 500
#define BATCH   64
#define N_DEL   8
#define NB      (N_NEUR*BATCH)     // 65536, layout [n][b], b fastest
#define HSLOTS  132                // ring: live window is 131 steps (writes t0,t0+1;
                                   // reads t0-129..t0-1) -> 132 proves no aliasing.
#define CAP     256                // per-(o,d) record capacity (mean 128, 12 sigma)
#define H1RING  64                 // h1 ring depth (steps), power of 2
#define LREC_MAX 1152              // >= 1024 + 8*3 padding

// ---------------------------------------------------------------------------
// inpT[t][c][b] = inputs[b][t][c]
__global__ __launch_bounds__(256) void transpose_inp(const float* __restrict__ inp,
                                                     float* __restrict__ inpT) {
    __shared__ float L[N_INP * 64];
    int t = blockIdx.x;
    int tid = threadIdx.x;                   // = c
    for (int b = 0; b < 64; ++b) {
        float v = inp[((size_t)b * T_STEPS + t) * N_INP + tid];
        L[tid * 64 + (b ^ (tid & 63))] = v;
    }
    __syncthreads();
    int lane = tid & 63;
    int wv   = tid >> 6;
    for (int cc = 0; cc < 64; ++cc) {
        int c = cc * 4 + wv;
        inpT[((size_t)t * N_INP + c) * 64 + lane] = L[c * 64 + (lane ^ (c & 63))];
    }
}

// w_inT[n][c] = w_in[c][n]
__global__ __launch_bounds__(256) void transpose_win(const float* __restrict__ w_in,
                                                     float* __restrict__ w_inT) {
    int i = blockIdx.x * 256 + threadIdx.x;  // 262144
    int n = i >> 8, c = i & 255;
    w_inT[i] = w_in[(size_t)c * N_NEUR + n];
}

// ---------------------------------------------------------------------------
// CSR build: for each (o,d), list of {G = sign[e]*|w[e][o]|, e*64} where
// dmap[d][e][o] == 1. Padded to a multiple of 4 with zero-records (G=0 -> inert).
// Records e-ASCENDING within each segment (load-bearing for bit-exact order).
// Parallel over (o,d): grid(16,8) (round-5, confirmed).
__global__ __launch_bounds__(64) void build_csr(const float* __restrict__ w,
                                                const float* __restrict__ signs,
                                                const float* __restrict__ dmap,
                                                uint2* __restrict__ recs,
                                                int* __restrict__ cnt) {
    int o = blockIdx.x * 64 + threadIdx.x;   // 16 blocks x 64 lanes
    int d = blockIdx.y;                      // 8
    int c = 0;
    uint2* seg = recs + ((size_t)o * N_DEL + d) * CAP;
    for (int e = 0; e < N_NEUR; ++e) {
        float m = dmap[((size_t)d * N_NEUR + e) * N_NEUR + o];  // coalesced over o
        if (m != 0.f) {
            float G = signs[e] * fabsf(w[(size_t)e * N_NEUR + o]);
            if (c < CAP) seg[c] = make_uint2(__float_as_uint(G), (unsigned)(e * 64));
            ++c;
        }
    }
    if (c > CAP) c = CAP;
    int c4 = (c + 3) & ~3;                // pad to multiple of 4
    for (; c < c4; ++c) seg[c] = make_uint2(0u, 0u);
    cnt[o * N_DEL + d] = c4;
}

// ---------------------------------------------------------------------------
// h1 ring precompute, 64 steps per launch (bit-exact, unchanged).
__global__ __launch_bounds__(256) void h1_chunk(int t0,
        const float* __restrict__ inpT, const float* __restrict__ w_inT,
        float* __restrict__ h1r) {
    __shared__ float Li[N_INP * 64];   // 64 KB
    __shared__ float Lp[4 * 64];
    int s     = t0 + blockIdx.x;
    int ntile = blockIdx.y;            // 16 tiles x 64 n
    int tid   = threadIdx.x;
    int lane  = tid & 63;
    int wv    = tid >> 6;
    const float4* src = (const float4*)(inpT + (size_t)s * (N_INP * 64));
    float4* dst = (float4*)Li;
    for (int k = tid; k < (N_INP * 64) / 4; k += 256) dst[k] = src[k];
    __syncthreads();
    for (int nn = 0; nn < 64; ++nn) {
        int n = ntile * 64 + nn;
        float hp = 0.f;
        const float* wr = w_inT + n * N_INP + wv * 64;   // uniform -> s_load
#pragma unroll 8
        for (int c2 = 0; c2 < 64; ++c2)
            hp = fmaf(Li[(wv * 64 + c2) * 64 + lane], wr[c2], hp);
        Lp[wv * 64 + lane] = hp;
        __syncthreads();
        if (wv == 0)
            h1r[(size_t)(s & (H1RING - 1)) * NB + n * 64 + lane] =
                Lp[lane] + Lp[64 + lane] + Lp[128 + lane] + Lp[192 + lane];
        __syncthreads();
    }
}

// ---------------------------------------------------------------------------
// Round-8 = Round-6 fused pair kernel (proven 8.58 ms) + two zero-numerics
// prologue micro-opts:
//  (1) cnt[] staged to LDS by 8 threads in parallel; prefix-sum over LDS
//      (was: 8 serial GLOBAL loads on thread 0 while 511 threads waited).
//  (2) Lrec staging is one flat parallel loop over the o's whole CAP-strided
//      record range (all loads independent, ~4 iterations) instead of 8
//      serial per-segment rounds. Identical Lrec contents bit-for-bit.
// Wave = one (d-pair, step) chain (dp = wv>>1, sidx = wv&1): 1024 blocks x
// 512 threads = 4 blocks/CU x 8 waves = 32 waves/CU (hardware cap).
// All hist reads are steps <= t0-1 (pre-launch); writes are t0,t0+1;
// HSLOTS=132 proves slot-disjointness.
__global__ __launch_bounds__(512, 8) void step_fused(int t0,
        const uint2* __restrict__ recs, const int* __restrict__ cnt,
        const int* __restrict__ delays, const float* __restrict__ h1r,
        const float* __restrict__ p,
        float* __restrict__ histc, float* __restrict__ mem,
        float* __restrict__ wp_arr, unsigned long long* __restrict__ spk) {
    __shared__ uint2 Lrec[LREC_MAX]; // ~9 KB: this o's record list, d-major, padded
    __shared__ int   Scnt[N_DEL];
    __shared__ int   off[N_DEL + 1];
    __shared__ float Lg0[4 * 64];    // partials step t0, [dp][b]
    __shared__ float Lg1[4 * 64];    // partials step t0+1
    int o    = blockIdx.x;
    int tid  = threadIdx.x;
    int lane = tid & 63;             // b
    int wv   = __builtin_amdgcn_readfirstlane(tid >> 6);   // 0..7

    if (tid < N_DEL) Scnt[tid] = cnt[o * N_DEL + tid];     // parallel global loads
    __syncthreads();
    if (tid == 0) {
        int s = 0;
        for (int d = 0; d < N_DEL; ++d) { off[d] = s; s += Scnt[d]; }  // LDS-only
        off[N_DEL] = s;
    }
    __syncthreads();
    // stage records d-major into LDS: flat parallel loop, independent loads
    {
        const unsigned long long* R =
            (const unsigned long long*)(recs + (size_t)o * N_DEL * CAP);
        for (int k = tid; k < N_DEL * CAP; k += 512) {
            int d  = k >> 8;             // CAP = 256
            int kl = k & (CAP - 1);
            if (kl < Scnt[d]) {
                unsigned long long v = __builtin_nontemporal_load(&R[k]);
                Lrec[off[d] + kl] = make_uint2((unsigned)v, (unsigned)(v >> 32));
            }
        }
    }
    int dp   = wv >> 1;              // d-pair 0..3 (== round-0 wave index)
    int sidx = wv & 1;               // step within the pair
    int j0 = dp * 2, j1 = j0 + 1;
    int dl0 = __builtin_amdgcn_readfirstlane(delays[j0]);
    int dl1 = __builtin_amdgcn_readfirstlane(delays[j1]);
    float pn = p[o];
    float pd = (pn < 0.f) ? 1.f : 0.f;
    int q  = lane >> 4;              // 0..3 : which record in the quad
    int bq = lane & 15;              // b-quad index

    // prefetch pointwise-tail inputs (block-private; latency hides under loop)
    int i_pw = o * 64 + lane;
    float m_pre   = mem[i_pw];
    float w_pre   = wp_arr[i_pw];
    float h1_pre0 = h1r[(size_t)(t0 & (H1RING - 1)) * NB + i_pw];
    float h1_pre1 = h1r[(size_t)((t0 + 1) & (H1RING - 1)) * NB + i_pw];
    __syncthreads();

    float4 acc = make_float4(0.f, 0.f, 0.f, 0.f);
#pragma unroll
    for (int seg = 0; seg < 2; ++seg) {
        int j   = seg ? j1 : j0;
        int dl  = seg ? dl1 : dl0;
        int tau = t0 + sidx - 1 - dl;    // this step's read slot (absolute)
        if (tau >= 0) {
            const float* hb = histc + (size_t)(tau % HSLOTS) * NB;
            int kb = off[j], ke = off[j + 1];
            int k = kb;
            for (; k + 8 <= ke; k += 8) {
                uint2 ra = Lrec[k + q];
                uint2 rb = Lrec[k + 4 + q];
                float ga = __uint_as_float(ra.x);
                float gb = __uint_as_float(rb.x);
                float4 a = *((const float4*)(hb + ra.y) + bq);
                float4 b = *((const float4*)(hb + rb.y) + bq);
                acc.x = fmaf(ga, a.x, acc.x); acc.y = fmaf(ga, a.y, acc.y);
                acc.z = fmaf(ga, a.z, acc.z); acc.w = fmaf(ga, a.w, acc.w);
                acc.x = fmaf(gb, b.x, acc.x); acc.y = fmaf(gb, b.y, acc.y);
                acc.z = fmaf(gb, b.z, acc.z); acc.w = fmaf(gb, b.w, acc.w);
            }
            if ((ke - kb) & 4) {
                uint2 r = Lrec[ke - 4 + q];
                float g = __uint_as_float(r.x);
                float4 a = *((const float4*)(hb + r.y) + bq);
                acc.x = fmaf(g, a.x, acc.x); acc.y = fmaf(g, a.y, acc.y);
                acc.z = fmaf(g, a.z, acc.z); acc.w = fmaf(g, a.w, acc.w);
            }
        }
    }
    // reduce across q (lane bits 4,5); lanes 0..15 then hold b = lane*4..+3
    acc.x += __shfl_xor(acc.x, 16); acc.x += __shfl_xor(acc.x, 32);
    acc.y += __shfl_xor(acc.y, 16); acc.y += __shfl_xor(acc.y, 32);
    acc.z += __shfl_xor(acc.z, 16); acc.z += __shfl_xor(acc.z, 32);
    acc.w += __shfl_xor(acc.w, 16); acc.w += __shfl_xor(acc.w, 32);
    if (lane < 16) {
        float* Lg = sidx ? Lg1 : Lg0;
        *((float4*)&Lg[dp * 64 + lane * 4]) = acc;
    }
    __syncthreads();
    // ---- pointwise(t0) then pointwise(t0+1): wave 0 (verbatim formulas)
    if (wv == 0) {
        float m = m_pre;
        float w = w_pre;
#pragma unroll
        for (int sx = 0; sx < 2; ++sx) {
            int s = t0 + sx;
            const float* Lg = sx ? Lg1 : Lg0;
            float syn = Lg[lane] + Lg[64 + lane] + Lg[128 + lane] + Lg[192 + lane];
            float h1 = sx ? h1_pre1 : h1_pre0;
            float out = (m - 1.f > 0.f) ? 1.f : 0.f;
            w = w * 0.95f + out * pn * (1.f + pd * w);
            histc[(size_t)(s % HSLOTS) * NB + i_pw] = out * (1.f + w);
            m = 0.9f * m + h1 + syn - out;
            unsigned long long mask = __ballot(out > 0.f);
            if (lane == 0) spk[(size_t)s * N_NEUR + o] = mask;
        }
        mem[i_pw] = m;
        wp_arr[i_pw] = w;
    }
}

// ---------------------------------------------------------------------------
// h2[t][b][o] = sum_n spk_bit(t,n,b) * w_out[n][o]
__global__ __launch_bounds__(256) void h2_gemm(const unsigned long long* __restrict__ spk,
                                               const float* __restrict__ w_out,
                                               float* __restrict__ h2) {
    int t = blockIdx.x;
    int lane = threadIdx.x & 63;     // = b
    int wv   = threadIdx.x >> 6;
    int o0 = wv * 8;
    float acc[8];
#pragma unroll
    for (int j = 0; j < 8; ++j) acc[j] = 0.f;
    for (int n = 0; n < N_NEUR; ++n) {
        unsigned long long mask = spk[(size_t)t * N_NEUR + n];   // uniform
        float s = (float)((mask >> lane) & 1ULL);
        const float* wr = w_out + n * N_OUTC + o0;               // uniform
#pragma unroll
        for (int j = 0; j < 8; ++j) acc[j] = fmaf(s, wr[j], acc[j]);
    }
#pragma unroll
    for (int j = 0; j < 8; ++j)
        h2[((size_t)t * BATCH + lane) * N_OUTC + o0 + j] = acc[j];
}

// out[b][t][o] : leaky-integrator scan over h2
__global__ __launch_bounds__(256) void out_scan(const float* __restrict__ h2,
                                                float* __restrict__ out) {
    int tid = blockIdx.x * 256 + threadIdx.x;   // 2048 = 64b * 32o
    int o = tid & 31;
    int b = tid >> 5;
    float acc = 0.f;
    for (int t = 0; t < T_STEPS; ++t) {
        acc = 0.9f * acc + h2[((size_t)t * BATCH + b) * N_OUTC + o];
        out[((size_t)b * T_STEPS + t) * N_OUTC + o] = acc;
    }
}

// ---------------------------------------------------------------------------
extern "C" void kernel_launch(void* const* d_in, const int* in_sizes, int n_in,
                              void* d_out, int out_size, void* d_ws, size_t ws_size,
                              hipStream_t stream) {
    (void)in_sizes; (void)n_in; (void)out_size; (void)ws_size;
    const float* inputs = (const float*)d_in[0];
    const float* w      = (const float*)d_in[1];
    const float* w_in   = (const float*)d_in[2];
    const float* w_out  = (const float*)d_in[3];
    const float* signs  = (const float*)d_in[4];
    const float* p      = (const float*)d_in[5];
    const float* dmap   = (const float*)d_in[6];
    const int*   delays = (const int*)d_in[7];
    float* out = (float*)d_out;

    // workspace layout (~106 MiB total, under proven 120.6 MiB)
    float* ws    = (float*)d_ws;
    float* inpT  = ws;                                    //  8,192,000 f
    float* w_inT = inpT + (size_t)T_STEPS * N_INP * 64;   //    262,144 f
    float* histc = w_inT + (size_t)N_NEUR * N_INP;        //  8,650,752 f
    float* h1r   = histc + (size_t)HSLOTS * NB;           //  4,194,304 f
    float* mem   = h1r + (size_t)H1RING * NB;             //     65,536 f
    float* wp    = mem + NB;                              //     65,536 f
    float* h2    = wp + NB;                               //  1,024,000 f
    int*   cnt   = (int*)(h2 + (size_t)T_STEPS * BATCH * N_OUTC);  // 8192 i
    uint2* recs  = (uint2*)(cnt + N_NEUR * N_DEL);        //  2,097,152 uint2
    unsigned long long* spk =
        (unsigned long long*)(recs + (size_t)N_NEUR * N_DEL * CAP); // 512,000 ull

    hipMemsetAsync(histc, 0, sizeof(float) * (size_t)HSLOTS * NB, stream);
    hipMemsetAsync(mem, 0, sizeof(float) * (size_t)2 * NB, stream);  // mem+wp adjacent

    transpose_inp<<<T_STEPS, 256, 0, stream>>>(inputs, inpT);
    transpose_win<<<(N_NEUR * N_INP) / 256, 256, 0, stream>>>(w_in, w_inT);
    build_csr<<<dim3(16, 8), 64, 0, stream>>>(w, signs, dmap, recs, cnt);

    for (int t0 = 0; t0 < T_STEPS; t0 += 2) {
        if ((t0 & (H1RING - 1)) == 0) {
            int ns = T_STEPS - t0; if (ns > H1RING) ns = H1RING;
            h1_chunk<<<dim3(ns, 16), 256, 0, stream>>>(t0, inpT, w_inT, h1r);
        }
        step_fused<<<N_NEUR, 512, 0, stream>>>(t0, recs, cnt, delays, h1r, p,
                                               histc, mem, wp, spk);
    }

    h2_gemm<<<T_STEPS, 256, 0, stream>>>(spk, w_out, h2);
    out_scan<<<8, 256, 0, stream>>>(h2, out);
}